// Round 12
// baseline (305.340 us; speedup 1.0000x reference)
//
#include <hip/hip_runtime.h>
#include <hip/hip_bf16.h>

// RPL_Asymm_3d_spconv: 3x (3-tap gathered GEMM -> BN(train) -> sigmoid), then (s1+s2+s3)*features
// N=131072, C=256. bf16 MFMA path.
//
// Round 12: LDS-bandwidth attack (round-11 counters: 48KB LDS/step vs 310cyc
// matrix -> util bound 41% = measured). Wave tile 64x128 (acc[4][8]), block
// 128 rows x 256 cols (full C):
//  - LDS bytes/MFMA 750 -> 563 (util bound ~55%)
//  - full-width N: each gathered A row fetched ONCE per axis (FETCH ~halves)
//  - SAME proven sync skeleton (distance-1 gload_lds + __syncthreads) -- pure
//    geometry change, no sync edits (rounds 7/8 raced on those)
//  - __launch_bounds__(256,2): VGPR<=256, no spill; 2 blocks/CU

#define NP 131072
#define CC 256
#define TILEA (128 * 32)   // A LDS tile elems (8 KiB)
#define TILEB (256 * 32)   // B LDS tile elems (16 KiB)

typedef __attribute__((ext_vector_type(4))) float f32x4;
typedef __attribute__((ext_vector_type(8))) short bf16x8;

__device__ __forceinline__ unsigned short f2bf(float f) {
    unsigned int u = __float_as_uint(f);
    u += 0x7FFFu + ((u >> 16) & 1u);   // RNE
    return (unsigned short)(u >> 16);
}
__device__ __forceinline__ float bf2f(unsigned short s) {
    return __uint_as_float(((unsigned int)s) << 16);
}

__device__ __forceinline__ void gload_lds16(const void* g, void* l) {
    __builtin_amdgcn_global_load_lds(
        (const __attribute__((address_space(1))) unsigned int*)g,
        (__attribute__((address_space(3))) unsigned int*)l, 16, 0, 0);
}

__global__ void zero_stats_k(float* stats) {
    int i = blockIdx.x * 256 + threadIdx.x;
    if (i < 3 * 2 * CC) stats[i] = 0.f;
}

__global__ void cast_features_k(const float* __restrict__ f, unsigned short* __restrict__ fb) {
    size_t e = ((size_t)blockIdx.x * 256 + threadIdx.x) * 8;
    const size_t tot = (size_t)(NP + 1) * CC;
    if (e >= tot) return;
    unsigned short tmp[8];
    if (e >= (size_t)NP * CC) {
        #pragma unroll
        for (int j = 0; j < 8; ++j) tmp[j] = 0;  // pad row
    } else {
        float4 v0 = *(const float4*)(f + e);
        float4 v1 = *(const float4*)(f + e + 4);
        tmp[0] = f2bf(v0.x); tmp[1] = f2bf(v0.y); tmp[2] = f2bf(v0.z); tmp[3] = f2bf(v0.w);
        tmp[4] = f2bf(v1.x); tmp[5] = f2bf(v1.y); tmp[6] = f2bf(v1.z); tmp[7] = f2bf(v1.w);
    }
    *(bf16x8*)(fb + e) = *(bf16x8*)tmp;
}

// wbT[m][cout][cin] = W_m[tap][cin][cout], m = axis*3+tap
__global__ void cast_weights_k(const float* __restrict__ W1, const float* __restrict__ W2,
                               const float* __restrict__ W3, unsigned short* __restrict__ wbT) {
    int bid  = blockIdx.x;        // 0..2303
    int m    = bid >> 8;          // 0..8
    int cout = bid & 255;
    int cin  = threadIdx.x;
    const float* W = (m < 3) ? W1 : (m < 6) ? W2 : W3;
    int tap = m - (m / 3) * 3;
    float v = W[((size_t)tap * CC + cin) * CC + cout];
    wbT[((size_t)m * CC + cout) * CC + cin] = f2bf(v);
}

#define MFMA16(a, b, c) __builtin_amdgcn_mfma_f32_16x16x32_bf16((a), (b), (c), 0, 0, 0)

__global__ __launch_bounds__(256, 2)
void gemm_conv_fused_k(const unsigned short* __restrict__ fb,
                       const unsigned short* __restrict__ wbT,
                       const int* __restrict__ nbr1, const int* __restrict__ nbr2,
                       const int* __restrict__ nbr3,
                       unsigned short* __restrict__ hbase,
                       float* __restrict__ statsBase) {
    __shared__ unsigned short As[2][TILEA];   // 2 x 8 KiB
    __shared__ unsigned short Bs[2][TILEB];   // 2 x 16 KiB
    __shared__ float colsum[256];
    __shared__ float colsq[256];

    const int axis = blockIdx.y;
    const int* nbr = (axis == 0) ? nbr1 : (axis == 1) ? nbr2 : nbr3;
    const unsigned short* wA = wbT + (size_t)axis * 3 * CC * CC;
    unsigned short* h = hbase + (size_t)axis * NP * CC;
    float* stats = statsBase + axis * 2 * CC;

    const int tid  = threadIdx.x;
    const int lane = tid & 63;
    const int wave = tid >> 6;
    // bijective XCD swizzle over 1024 blocks (1024 % 8 == 0)
    const int bx   = blockIdx.x;
    const int swzb = (bx & 7) * 128 + (bx >> 3);
    const int rowBase = swzb * 128;

    colsum[tid] = 0.f; colsq[tid] = 0.f;

    // A staging: 2 granules/thread (128x32 tile); B staging: 4 granules/thread (256x32)
    int srcOffA[2], gA0[2], gA1[2], gA2[2];
    #pragma unroll
    for (int u = 0; u < 2; ++u) {
        int idx = u * 256 + tid;
        int r = idx >> 2, p = idx & 3;
        srcOffA[u] = (p ^ ((r >> 1) & 3)) * 8;   // inverse swizzle on source
        int gi = rowBase + r;
        gA0[u] = nbr[(size_t)gi * 3 + 0];
        gA1[u] = nbr[(size_t)gi * 3 + 1];
        gA2[u] = nbr[(size_t)gi * 3 + 2];
    }
    int srcOffB[4], bRow[4];
    #pragma unroll
    for (int u = 0; u < 4; ++u) {
        int idx = u * 256 + tid;
        int r = idx >> 2, p = idx & 3;
        srcOffB[u] = (p ^ ((r >> 1) & 3)) * 8;
        bRow[u] = r;                              // col index 0..255 (full width)
    }

#define STAGE_A(u, Abuf, tapsel, kkE) do {                                      \
        int gr_ = ((tapsel) == 0) ? gA0[u] : ((tapsel) == 1) ? gA1[u] : gA2[u]; \
        gload_lds16(fb + (size_t)gr_ * CC + (kkE) + srcOffA[u],                 \
                    (Abuf) + ((u) * 256 + tid) * 8);                            \
    } while (0)
#define STAGE_B(u, Bbuf, wTt, kkE)                                              \
        gload_lds16((wTt) + (size_t)bRow[u] * CC + (kkE) + srcOffB[u],          \
                    (Bbuf) + ((u) * 256 + tid) * 8)

    const int wr = wave >> 1;             // 0..1 row half (64 rows each)
    const int wc = wave & 1;              // 0..1 col half (128 cols each)
    const int fr = lane & 15;
    const int kq = lane >> 4;
    const int chunkOff = (kq ^ ((fr >> 1) & 3)) * 8;  // read-side swizzle (elems)
    const int rA = wr * 64 + fr;
    const int rB = wc * 128 + fr;

    f32x4 acc[4][8] = {};

    // prologue: stage K-step 0 (tap 0, kk 0)
    STAGE_A(0, As[0], 0, 0); STAGE_A(1, As[0], 0, 0);
    STAGE_B(0, Bs[0], wA, 0); STAGE_B(1, Bs[0], wA, 0);
    STAGE_B(2, Bs[0], wA, 0); STAGE_B(3, Bs[0], wA, 0);
    __syncthreads();

    for (int t = 0; t < 24; ++t) {
        const unsigned short* Ac = As[t & 1];
        const unsigned short* Bc = Bs[t & 1];
        unsigned short* An = As[(t + 1) & 1];
        unsigned short* Bn = Bs[(t + 1) & 1];
        const int t1 = t + 1;
        const int tap1 = t1 >> 3;
        const int kk1 = (t1 & 7) * 32;

        if (t < 23) {
            const unsigned short* wT1 = wA + (size_t)tap1 * CC * CC;
            STAGE_A(0, An, tap1, kk1); STAGE_A(1, An, tap1, kk1);
            STAGE_B(0, Bn, wT1, kk1);  STAGE_B(1, Bn, wT1, kk1);
            STAGE_B(2, Bn, wT1, kk1);  STAGE_B(3, Bn, wT1, kk1);
        }

        bf16x8 aF[4];
        #pragma unroll
        for (int m = 0; m < 4; ++m)
            aF[m] = *(const bf16x8*)(Ac + (rA + m * 16) * 32 + chunkOff);

        #pragma unroll
        for (int half = 0; half < 2; ++half) {
            bf16x8 bF[4];
            #pragma unroll
            for (int n = 0; n < 4; ++n)
                bF[n] = *(const bf16x8*)(Bc + (rB + (half * 4 + n) * 16) * 32 + chunkOff);
            #pragma unroll
            for (int m = 0; m < 4; ++m)
                #pragma unroll
                for (int n = 0; n < 4; ++n)
                    acc[m][half * 4 + n] = MFMA16(aF[m], bF[n], acc[m][half * 4 + n]);
        }

        __syncthreads();
    }

    // epilogue: C/D layout col=lane&15, row=(lane>>4)*4+reg; h store + fused stats
    const int orow = (lane >> 4) * 4;
    float psum[8], psq[8];
    #pragma unroll
    for (int n = 0; n < 8; ++n) { psum[n] = 0.f; psq[n] = 0.f; }
    #pragma unroll
    for (int m = 0; m < 4; ++m) {
        #pragma unroll
        for (int n = 0; n < 8; ++n) {
            int col = wc * 128 + n * 16 + fr;
            int row = rowBase + wr * 64 + m * 16 + orow;
            #pragma unroll
            for (int j = 0; j < 4; ++j) {
                unsigned short hb = f2bf(acc[m][n][j]);
                float v = bf2f(hb);
                h[(size_t)(row + j) * CC + col] = hb;
                psum[n] += v;
                psq[n]  += v * v;
            }
        }
    }
    #pragma unroll
    for (int n = 0; n < 8; ++n) {
        psum[n] += __shfl_xor(psum[n], 16);
        psum[n] += __shfl_xor(psum[n], 32);
        psq[n]  += __shfl_xor(psq[n], 16);
        psq[n]  += __shfl_xor(psq[n], 32);
    }
    if ((lane >> 4) == 0) {
        #pragma unroll
        for (int n = 0; n < 8; ++n) {
            int cl = wc * 128 + n * 16 + fr;   // local col 0..255
            atomicAdd(&colsum[cl], psum[n]);
            atomicAdd(&colsq[cl],  psq[n]);
        }
    }
    __syncthreads();
    atomicAdd(&stats[tid],      colsum[tid]);
    atomicAdd(&stats[CC + tid], colsq[tid]);
#undef STAGE_A
#undef STAGE_B
}

__global__ void finalize3_k(const float* __restrict__ stats,
                            const float* __restrict__ g1, const float* __restrict__ b1,
                            const float* __restrict__ g2, const float* __restrict__ b2,
                            const float* __restrict__ g3, const float* __restrict__ b3,
                            float* __restrict__ ss) {
    int a = blockIdx.x;
    int c = threadIdx.x;
    const float* g = (a == 0) ? g1 : (a == 1) ? g2 : g3;
    const float* b = (a == 0) ? b1 : (a == 1) ? b2 : b3;
    const float* st = stats + a * 2 * CC;
    float* s = ss + a * 2 * CC;
    float mu  = st[c] * (1.f / NP);
    float var = st[CC + c] * (1.f / NP) - mu * mu;
    float sc  = g[c] * rsqrtf(var + 1e-5f);
    s[c]      = sc;
    s[CC + c] = b[c] - mu * sc;
}

// out = (sigmoid(a1*h1+c1) + sigmoid(a2*h2+c2) + sigmoid(a3*h3+c3)) * feat(bf16)
__global__ void apply3_k(const unsigned short* __restrict__ h1,
                         const unsigned short* __restrict__ h2,
                         const unsigned short* __restrict__ h3,
                         const float* __restrict__ ss,
                         const unsigned short* __restrict__ fb, float* __restrict__ out) {
    size_t e = ((size_t)blockIdx.x * 256 + threadIdx.x) * 8;
    int c0 = (int)(e & (CC - 1));
    bf16x8 v1 = *(const bf16x8*)(h1 + e);
    bf16x8 v2 = *(const bf16x8*)(h2 + e);
    bf16x8 v3 = *(const bf16x8*)(h3 + e);
    bf16x8 fv = *(const bf16x8*)(fb + e);
    float s[8];
    #pragma unroll
    for (int j = 0; j < 8; ++j) {
        float z1 = ss[c0 + j]          * bf2f((unsigned short)v1[j]) + ss[CC + c0 + j];
        float z2 = ss[2 * CC + c0 + j] * bf2f((unsigned short)v2[j]) + ss[3 * CC + c0 + j];
        float z3 = ss[4 * CC + c0 + j] * bf2f((unsigned short)v3[j]) + ss[5 * CC + c0 + j];
        float sg = 1.f / (1.f + __expf(-z1)) + 1.f / (1.f + __expf(-z2)) + 1.f / (1.f + __expf(-z3));
        s[j] = sg * bf2f((unsigned short)fv[j]);
    }
    f32x4* o = (f32x4*)(out + e);
    f32x4 o0 = {s[0], s[1], s[2], s[3]};
    f32x4 o1 = {s[4], s[5], s[6], s[7]};
    __builtin_nontemporal_store(o0, o);
    __builtin_nontemporal_store(o1, o + 1);
}

extern "C" void kernel_launch(void* const* d_in, const int* in_sizes, int n_in,
                              void* d_out, int out_size, void* d_ws, size_t ws_size,
                              hipStream_t stream) {
    const float* feat = (const float*)d_in[0];
    const float* W1   = (const float*)d_in[1];
    const float* W2   = (const float*)d_in[2];
    const float* W3   = (const float*)d_in[3];
    const float* g1   = (const float*)d_in[4];
    const float* b1   = (const float*)d_in[5];
    const float* g2   = (const float*)d_in[6];
    const float* b2   = (const float*)d_in[7];
    const float* g3   = (const float*)d_in[8];
    const float* b3   = (const float*)d_in[9];
    const int* nbr1   = (const int*)d_in[10];
    const int* nbr2   = (const int*)d_in[11];
    const int* nbr3   = (const int*)d_in[12];
    float* out = (float*)d_out;

    char* w = (char*)d_ws;
    unsigned short* fb   = (unsigned short*)w;  w += (size_t)(NP + 1) * CC * 2;
    unsigned short* wbT  = (unsigned short*)w;  w += (size_t)9 * CC * CC * 2;
    float* stats         = (float*)w;           w += (size_t)3 * 2 * CC * 4;
    float* ss            = (float*)w;           w += (size_t)3 * 2 * CC * 4;
    unsigned short* hbuf = (unsigned short*)w;  // 3 * N * C bf16

    zero_stats_k<<<6, 256, 0, stream>>>(stats);
    {
        size_t tot = (size_t)(NP + 1) * CC / 8;
        int blocks = (int)((tot + 255) / 256);
        cast_features_k<<<blocks, 256, 0, stream>>>(feat, fb);
    }
    cast_weights_k<<<2304, 256, 0, stream>>>(W1, W2, W3, wbT);

    gemm_conv_fused_k<<<dim3(1024, 3), 256, 0, stream>>>(fb, wbT, nbr1, nbr2, nbr3,
                                                         hbuf, stats);
    finalize3_k<<<3, 256, 0, stream>>>(stats, g1, b1, g2, b2, g3, b3, ss);
    apply3_k<<<16384, 256, 0, stream>>>(hbuf,
                                        hbuf + (size_t)NP * CC,
                                        hbuf + (size_t)2 * NP * CC,
                                        ss, fb, out);
}

// Round 13
// 294.392 us; speedup vs baseline: 1.0372x; 1.0372x over previous
//
#include <hip/hip_runtime.h>
#include <hip/hip_bf16.h>

// RPL_Asymm_3d_spconv: 3x (3-tap gathered GEMM -> BN(train) -> sigmoid), then (s1+s2+s3)*features
// N=131072, C=256. bf16 MFMA path.
//
// Round 13 = Round 11 gemm (proven best: 128x128 tile, 64x64 wave, BK=32,
// distance-1 gload_lds + __syncthreads, 4 blocks/CU, XCD swizzle, fused stats)
// + plumbing harvest:
//  - ONE cast dispatch (features + weights + stats-zero merged)
//  - finalize inlined into apply3 (stats -> scale/shift per-thread; L1-resident)
//  - NT h-loads in apply (round-6 best variant)
// 6 dispatches -> 3.

#define NP 131072
#define CC 256
#define TILEE (128 * 32)   // elems per LDS tile buffer
#define NFEAT_BLOCKS 16385 // ceil((NP+1)*CC/8 / 256)

typedef __attribute__((ext_vector_type(4))) float f32x4;
typedef __attribute__((ext_vector_type(8))) short bf16x8;

__device__ __forceinline__ unsigned short f2bf(float f) {
    unsigned int u = __float_as_uint(f);
    u += 0x7FFFu + ((u >> 16) & 1u);   // RNE
    return (unsigned short)(u >> 16);
}
__device__ __forceinline__ float bf2f(unsigned short s) {
    return __uint_as_float(((unsigned int)s) << 16);
}

__device__ __forceinline__ void gload_lds16(const void* g, void* l) {
    __builtin_amdgcn_global_load_lds(
        (const __attribute__((address_space(1))) unsigned int*)g,
        (__attribute__((address_space(3))) unsigned int*)l, 16, 0, 0);
}

// merged: feature cast | weight cast+transpose | stats zeroing
__global__ void cast_all_k(const float* __restrict__ f,
                           const float* __restrict__ W1, const float* __restrict__ W2,
                           const float* __restrict__ W3,
                           unsigned short* __restrict__ fb, unsigned short* __restrict__ wbT,
                           float* __restrict__ stats) {
    const int bid = blockIdx.x;
    const int tid = threadIdx.x;
    if (bid < 6) stats[bid * 256 + tid] = 0.f;   // 3*2*256 floats

    if (bid < NFEAT_BLOCKS) {
        size_t e = ((size_t)bid * 256 + tid) * 8;
        const size_t tot = (size_t)(NP + 1) * CC;
        if (e >= tot) return;
        unsigned short tmp[8];
        if (e >= (size_t)NP * CC) {
            #pragma unroll
            for (int j = 0; j < 8; ++j) tmp[j] = 0;  // pad row
        } else {
            float4 v0 = *(const float4*)(f + e);
            float4 v1 = *(const float4*)(f + e + 4);
            tmp[0] = f2bf(v0.x); tmp[1] = f2bf(v0.y); tmp[2] = f2bf(v0.z); tmp[3] = f2bf(v0.w);
            tmp[4] = f2bf(v1.x); tmp[5] = f2bf(v1.y); tmp[6] = f2bf(v1.z); tmp[7] = f2bf(v1.w);
        }
        *(bf16x8*)(fb + e) = *(bf16x8*)tmp;
    } else {
        int wbid = bid - NFEAT_BLOCKS;    // 0..2303
        int m    = wbid >> 8;             // 0..8
        int cout = wbid & 255;
        int cin  = tid;
        const float* W = (m < 3) ? W1 : (m < 6) ? W2 : W3;
        int tap = m - (m / 3) * 3;
        float v = W[((size_t)tap * CC + cin) * CC + cout];
        wbT[((size_t)m * CC + cout) * CC + cin] = f2bf(v);
    }
}

#define MFMA16(a, b, c) __builtin_amdgcn_mfma_f32_16x16x32_bf16((a), (b), (c), 0, 0, 0)

__global__ __launch_bounds__(256, 4)
void gemm_conv_fused_k(const unsigned short* __restrict__ fb,
                       const unsigned short* __restrict__ wbT,
                       const int* __restrict__ nbr1, const int* __restrict__ nbr2,
                       const int* __restrict__ nbr3,
                       unsigned short* __restrict__ hbase,
                       float* __restrict__ statsBase) {
    __shared__ unsigned short As[2][TILEE];   // 2 x 8 KiB
    __shared__ unsigned short Bs[2][TILEE];   // 2 x 8 KiB
    __shared__ float colsum[128];
    __shared__ float colsq[128];

    const int axis = blockIdx.y;
    const int* nbr = (axis == 0) ? nbr1 : (axis == 1) ? nbr2 : nbr3;
    const unsigned short* wA = wbT + (size_t)axis * 3 * CC * CC;
    unsigned short* h = hbase + (size_t)axis * NP * CC;
    float* stats = statsBase + axis * 2 * CC;

    const int tid  = threadIdx.x;
    const int lane = tid & 63;
    const int wave = tid >> 6;
    // bijective XCD swizzle over 2048 blocks (2048 % 8 == 0)
    const int bx   = blockIdx.x;
    const int swzb = (bx & 7) * 256 + (bx >> 3);
    const int rowBase = (swzb >> 1) * 128;
    const int colBase = (swzb & 1) * 128;

    if (tid < 128) { colsum[tid] = 0.f; colsq[tid] = 0.f; }

    // staging constants: 2 A-granules + 2 B-granules per thread per K-step
    int srcOff[2], gA0[2], gA1[2], gA2[2], bRow[2];
    #pragma unroll
    for (int u = 0; u < 2; ++u) {
        int idx = u * 256 + tid;          // 16B-granule index in 128x32 tile
        int r = idx >> 2, p = idx & 3;
        srcOff[u] = (p ^ ((r >> 1) & 3)) * 8;   // inverse swizzle on source
        int gi = rowBase + r;
        gA0[u] = nbr[(size_t)gi * 3 + 0];
        gA1[u] = nbr[(size_t)gi * 3 + 1];
        gA2[u] = nbr[(size_t)gi * 3 + 2];
        bRow[u] = colBase + r;
    }

#define STAGE_A(u, Abuf, tapsel, kkE) do {                                      \
        int gr_ = ((tapsel) == 0) ? gA0[u] : ((tapsel) == 1) ? gA1[u] : gA2[u]; \
        gload_lds16(fb + (size_t)gr_ * CC + (kkE) + srcOff[u],                  \
                    (Abuf) + ((u) * 256 + tid) * 8);                            \
    } while (0)
#define STAGE_B(u, Bbuf, wTt, kkE)                                              \
        gload_lds16((wTt) + (size_t)bRow[u] * CC + (kkE) + srcOff[u],           \
                    (Bbuf) + ((u) * 256 + tid) * 8)

    const int wr = (wave >> 1) & 1;
    const int wc = wave & 1;
    const int fr = lane & 15;
    const int kq = lane >> 4;
    const int chunkOff = (kq ^ ((fr >> 1) & 3)) * 8;  // read-side swizzle (elems)
    const int rA = wr * 64 + fr;
    const int rB = wc * 64 + fr;

    f32x4 acc[4][4] = {};

    // prologue: stage K-step 0 (tap 0, kk 0)
    STAGE_A(0, As[0], 0, 0); STAGE_A(1, As[0], 0, 0);
    STAGE_B(0, Bs[0], wA, 0); STAGE_B(1, Bs[0], wA, 0);
    __syncthreads();

    for (int t = 0; t < 24; ++t) {
        const unsigned short* Ac = As[t & 1];
        const unsigned short* Bc = Bs[t & 1];
        unsigned short* An = As[(t + 1) & 1];
        unsigned short* Bn = Bs[(t + 1) & 1];
        const int t1 = t + 1;
        const int tap1 = t1 >> 3;
        const int kk1 = (t1 & 7) * 32;

        if (t < 23) {
            const unsigned short* wT1 = wA + (size_t)tap1 * CC * CC;
            STAGE_A(0, An, tap1, kk1); STAGE_A(1, An, tap1, kk1);
            STAGE_B(0, Bn, wT1, kk1);  STAGE_B(1, Bn, wT1, kk1);
        }

        bf16x8 aF[4], bF[4];
        #pragma unroll
        for (int m = 0; m < 4; ++m)
            aF[m] = *(const bf16x8*)(Ac + (rA + m * 16) * 32 + chunkOff);
        #pragma unroll
        for (int n = 0; n < 4; ++n)
            bF[n] = *(const bf16x8*)(Bc + (rB + n * 16) * 32 + chunkOff);
        #pragma unroll
        for (int m = 0; m < 4; ++m)
            #pragma unroll
            for (int n = 0; n < 4; ++n)
                acc[m][n] = MFMA16(aF[m], bF[n], acc[m][n]);

        __syncthreads();
    }

    // epilogue: C/D layout col=lane&15, row=(lane>>4)*4+reg; h store + fused stats
    const int orow = (lane >> 4) * 4;
    float psum[4], psq[4];
    #pragma unroll
    for (int n = 0; n < 4; ++n) { psum[n] = 0.f; psq[n] = 0.f; }
    #pragma unroll
    for (int m = 0; m < 4; ++m) {
        #pragma unroll
        for (int n = 0; n < 4; ++n) {
            int col = colBase + wc * 64 + n * 16 + fr;
            int row = rowBase + wr * 64 + m * 16 + orow;
            #pragma unroll
            for (int j = 0; j < 4; ++j) {
                unsigned short hb = f2bf(acc[m][n][j]);
                float v = bf2f(hb);
                h[(size_t)(row + j) * CC + col] = hb;
                psum[n] += v;
                psq[n]  += v * v;
            }
        }
    }
    #pragma unroll
    for (int n = 0; n < 4; ++n) {
        psum[n] += __shfl_xor(psum[n], 16);
        psum[n] += __shfl_xor(psum[n], 32);
        psq[n]  += __shfl_xor(psq[n], 16);
        psq[n]  += __shfl_xor(psq[n], 32);
    }
    if ((lane >> 4) == 0) {
        #pragma unroll
        for (int n = 0; n < 4; ++n) {
            int cl = wc * 64 + n * 16 + fr;   // local col 0..127
            atomicAdd(&colsum[cl], psum[n]);
            atomicAdd(&colsq[cl],  psq[n]);
        }
    }
    __syncthreads();
    if (tid < 128) {
        int c = colBase + tid;
        atomicAdd(&stats[c],      colsum[tid]);
        atomicAdd(&stats[CC + c], colsq[tid]);
    }
#undef STAGE_A
#undef STAGE_B
}

// out = (sum_a sigmoid(sc_a*h_a + sh_a)) * feat, with BN scale/shift computed
// inline from stats (L1-resident, deterministic across blocks).
__global__ void apply3_k(const unsigned short* __restrict__ h1,
                         const unsigned short* __restrict__ h2,
                         const unsigned short* __restrict__ h3,
                         const float* __restrict__ stats,
                         const float* __restrict__ g1, const float* __restrict__ b1,
                         const float* __restrict__ g2, const float* __restrict__ b2,
                         const float* __restrict__ g3, const float* __restrict__ b3,
                         const unsigned short* __restrict__ fb, float* __restrict__ out) {
    size_t e = ((size_t)blockIdx.x * 256 + threadIdx.x) * 8;
    int c0 = (int)(e & (CC - 1));
    bf16x8 v1 = __builtin_nontemporal_load((const bf16x8*)(h1 + e));
    bf16x8 v2 = __builtin_nontemporal_load((const bf16x8*)(h2 + e));
    bf16x8 v3 = __builtin_nontemporal_load((const bf16x8*)(h3 + e));
    bf16x8 fv = *(const bf16x8*)(fb + e);
    const float* gs[3] = {g1, g2, g3};
    const float* bs[3] = {b1, b2, b3};
    float s[8];
    #pragma unroll
    for (int j = 0; j < 8; ++j) {
        int c = c0 + j;
        float hv[3] = {bf2f((unsigned short)v1[j]), bf2f((unsigned short)v2[j]),
                       bf2f((unsigned short)v3[j])};
        float sg = 0.f;
        #pragma unroll
        for (int a = 0; a < 3; ++a) {
            const float* st = stats + a * 2 * CC;
            float mu  = st[c] * (1.f / NP);
            float var = st[CC + c] * (1.f / NP) - mu * mu;
            float sc  = gs[a][c] * rsqrtf(var + 1e-5f);
            float z   = sc * hv[a] + (bs[a][c] - mu * sc);
            sg += 1.f / (1.f + __expf(-z));
        }
        s[j] = sg * bf2f((unsigned short)fv[j]);
    }
    f32x4* o = (f32x4*)(out + e);
    f32x4 o0 = {s[0], s[1], s[2], s[3]};
    f32x4 o1 = {s[4], s[5], s[6], s[7]};
    __builtin_nontemporal_store(o0, o);
    __builtin_nontemporal_store(o1, o + 1);
}

extern "C" void kernel_launch(void* const* d_in, const int* in_sizes, int n_in,
                              void* d_out, int out_size, void* d_ws, size_t ws_size,
                              hipStream_t stream) {
    const float* feat = (const float*)d_in[0];
    const float* W1   = (const float*)d_in[1];
    const float* W2   = (const float*)d_in[2];
    const float* W3   = (const float*)d_in[3];
    const float* g1   = (const float*)d_in[4];
    const float* b1   = (const float*)d_in[5];
    const float* g2   = (const float*)d_in[6];
    const float* b2   = (const float*)d_in[7];
    const float* g3   = (const float*)d_in[8];
    const float* b3   = (const float*)d_in[9];
    const int* nbr1   = (const int*)d_in[10];
    const int* nbr2   = (const int*)d_in[11];
    const int* nbr3   = (const int*)d_in[12];
    float* out = (float*)d_out;

    char* w = (char*)d_ws;
    unsigned short* fb   = (unsigned short*)w;  w += (size_t)(NP + 1) * CC * 2;
    unsigned short* wbT  = (unsigned short*)w;  w += (size_t)9 * CC * CC * 2;
    float* stats         = (float*)w;           w += (size_t)3 * 2 * CC * 4;
    float* ss            = (float*)w;           w += (size_t)3 * 2 * CC * 4;  // unused (kept layout)
    unsigned short* hbuf = (unsigned short*)w;  // 3 * N * C bf16
    (void)ss;

    cast_all_k<<<NFEAT_BLOCKS + 2304, 256, 0, stream>>>(feat, W1, W2, W3, fb, wbT, stats);

    gemm_conv_fused_k<<<dim3(2048, 3), 256, 0, stream>>>(fb, wbT, nbr1, nbr2, nbr3,
                                                         hbuf, stats);

    apply3_k<<<16384, 256, 0, stream>>>(hbuf,
                                        hbuf + (size_t)NP * CC,
                                        hbuf + (size_t)2 * NP * CC,
                                        stats, g1, b1, g2, b2, g3, b3,
                                        fb, out);
}

// Round 14
// 265.842 us; speedup vs baseline: 1.1486x; 1.1074x over previous
//
#include <hip/hip_runtime.h>
#include <hip/hip_bf16.h>

// RPL_Asymm_3d_spconv: 3x (3-tap gathered GEMM -> BN(train) -> sigmoid), then (s1+s2+s3)*features
// N=131072, C=256. bf16 MFMA path.
//
// Round 14 = best-measured assembly (no new structure):
//  - gemm: round-11 exact (128x128 tile, 64x64 wave, BK=32, distance-1
//    gload_lds + __syncthreads, 4 blocks/CU, XCD swizzle, fused BN stats)
//  - cast: merged cast_all (features + weights + stats-zero, one dispatch)
//  - finalize: separate 3-block kernel (r13's inlined version cost +13us:
//    96 extra VMEM loads/thread blew apply's issue budget)
//  - apply: precomputed ss + NT h-loads (r6 best) + NT stores

#define NP 131072
#define CC 256
#define TILEE (128 * 32)   // elems per LDS tile buffer
#define NFEAT_BLOCKS 16385 // ceil((NP+1)*CC/8 / 256)

typedef __attribute__((ext_vector_type(4))) float f32x4;
typedef __attribute__((ext_vector_type(8))) short bf16x8;

__device__ __forceinline__ unsigned short f2bf(float f) {
    unsigned int u = __float_as_uint(f);
    u += 0x7FFFu + ((u >> 16) & 1u);   // RNE
    return (unsigned short)(u >> 16);
}
__device__ __forceinline__ float bf2f(unsigned short s) {
    return __uint_as_float(((unsigned int)s) << 16);
}

__device__ __forceinline__ void gload_lds16(const void* g, void* l) {
    __builtin_amdgcn_global_load_lds(
        (const __attribute__((address_space(1))) unsigned int*)g,
        (__attribute__((address_space(3))) unsigned int*)l, 16, 0, 0);
}

// merged: feature cast | weight cast+transpose | stats zeroing
__global__ void cast_all_k(const float* __restrict__ f,
                           const float* __restrict__ W1, const float* __restrict__ W2,
                           const float* __restrict__ W3,
                           unsigned short* __restrict__ fb, unsigned short* __restrict__ wbT,
                           float* __restrict__ stats) {
    const int bid = blockIdx.x;
    const int tid = threadIdx.x;
    if (bid < 6) stats[bid * 256 + tid] = 0.f;   // 3*2*256 floats

    if (bid < NFEAT_BLOCKS) {
        size_t e = ((size_t)bid * 256 + tid) * 8;
        const size_t tot = (size_t)(NP + 1) * CC;
        if (e >= tot) return;
        unsigned short tmp[8];
        if (e >= (size_t)NP * CC) {
            #pragma unroll
            for (int j = 0; j < 8; ++j) tmp[j] = 0;  // pad row
        } else {
            float4 v0 = *(const float4*)(f + e);
            float4 v1 = *(const float4*)(f + e + 4);
            tmp[0] = f2bf(v0.x); tmp[1] = f2bf(v0.y); tmp[2] = f2bf(v0.z); tmp[3] = f2bf(v0.w);
            tmp[4] = f2bf(v1.x); tmp[5] = f2bf(v1.y); tmp[6] = f2bf(v1.z); tmp[7] = f2bf(v1.w);
        }
        *(bf16x8*)(fb + e) = *(bf16x8*)tmp;
    } else {
        int wbid = bid - NFEAT_BLOCKS;    // 0..2303
        int m    = wbid >> 8;             // 0..8
        int cout = wbid & 255;
        int cin  = tid;
        const float* W = (m < 3) ? W1 : (m < 6) ? W2 : W3;
        int tap = m - (m / 3) * 3;
        float v = W[((size_t)tap * CC + cin) * CC + cout];
        wbT[((size_t)m * CC + cout) * CC + cin] = f2bf(v);
    }
}

#define MFMA16(a, b, c) __builtin_amdgcn_mfma_f32_16x16x32_bf16((a), (b), (c), 0, 0, 0)

__global__ __launch_bounds__(256, 4)
void gemm_conv_fused_k(const unsigned short* __restrict__ fb,
                       const unsigned short* __restrict__ wbT,
                       const int* __restrict__ nbr1, const int* __restrict__ nbr2,
                       const int* __restrict__ nbr3,
                       unsigned short* __restrict__ hbase,
                       float* __restrict__ statsBase) {
    __shared__ unsigned short As[2][TILEE];   // 2 x 8 KiB
    __shared__ unsigned short Bs[2][TILEE];   // 2 x 8 KiB
    __shared__ float colsum[128];
    __shared__ float colsq[128];

    const int axis = blockIdx.y;
    const int* nbr = (axis == 0) ? nbr1 : (axis == 1) ? nbr2 : nbr3;
    const unsigned short* wA = wbT + (size_t)axis * 3 * CC * CC;
    unsigned short* h = hbase + (size_t)axis * NP * CC;
    float* stats = statsBase + axis * 2 * CC;

    const int tid  = threadIdx.x;
    const int lane = tid & 63;
    const int wave = tid >> 6;
    // bijective XCD swizzle over 2048 blocks (2048 % 8 == 0)
    const int bx   = blockIdx.x;
    const int swzb = (bx & 7) * 256 + (bx >> 3);
    const int rowBase = (swzb >> 1) * 128;
    const int colBase = (swzb & 1) * 128;

    if (tid < 128) { colsum[tid] = 0.f; colsq[tid] = 0.f; }

    // staging constants: 2 A-granules + 2 B-granules per thread per K-step
    int srcOff[2], gA0[2], gA1[2], gA2[2], bRow[2];
    #pragma unroll
    for (int u = 0; u < 2; ++u) {
        int idx = u * 256 + tid;          // 16B-granule index in 128x32 tile
        int r = idx >> 2, p = idx & 3;
        srcOff[u] = (p ^ ((r >> 1) & 3)) * 8;   // inverse swizzle on source
        int gi = rowBase + r;
        gA0[u] = nbr[(size_t)gi * 3 + 0];
        gA1[u] = nbr[(size_t)gi * 3 + 1];
        gA2[u] = nbr[(size_t)gi * 3 + 2];
        bRow[u] = colBase + r;
    }

#define STAGE_A(u, Abuf, tapsel, kkE) do {                                      \
        int gr_ = ((tapsel) == 0) ? gA0[u] : ((tapsel) == 1) ? gA1[u] : gA2[u]; \
        gload_lds16(fb + (size_t)gr_ * CC + (kkE) + srcOff[u],                  \
                    (Abuf) + ((u) * 256 + tid) * 8);                            \
    } while (0)
#define STAGE_B(u, Bbuf, wTt, kkE)                                              \
        gload_lds16((wTt) + (size_t)bRow[u] * CC + (kkE) + srcOff[u],           \
                    (Bbuf) + ((u) * 256 + tid) * 8)

    const int wr = (wave >> 1) & 1;
    const int wc = wave & 1;
    const int fr = lane & 15;
    const int kq = lane >> 4;
    const int chunkOff = (kq ^ ((fr >> 1) & 3)) * 8;  // read-side swizzle (elems)
    const int rA = wr * 64 + fr;
    const int rB = wc * 64 + fr;

    f32x4 acc[4][4] = {};

    // prologue: stage K-step 0 (tap 0, kk 0)
    STAGE_A(0, As[0], 0, 0); STAGE_A(1, As[0], 0, 0);
    STAGE_B(0, Bs[0], wA, 0); STAGE_B(1, Bs[0], wA, 0);
    __syncthreads();

    for (int t = 0; t < 24; ++t) {
        const unsigned short* Ac = As[t & 1];
        const unsigned short* Bc = Bs[t & 1];
        unsigned short* An = As[(t + 1) & 1];
        unsigned short* Bn = Bs[(t + 1) & 1];
        const int t1 = t + 1;
        const int tap1 = t1 >> 3;
        const int kk1 = (t1 & 7) * 32;

        if (t < 23) {
            const unsigned short* wT1 = wA + (size_t)tap1 * CC * CC;
            STAGE_A(0, An, tap1, kk1); STAGE_A(1, An, tap1, kk1);
            STAGE_B(0, Bn, wT1, kk1);  STAGE_B(1, Bn, wT1, kk1);
        }

        bf16x8 aF[4], bF[4];
        #pragma unroll
        for (int m = 0; m < 4; ++m)
            aF[m] = *(const bf16x8*)(Ac + (rA + m * 16) * 32 + chunkOff);
        #pragma unroll
        for (int n = 0; n < 4; ++n)
            bF[n] = *(const bf16x8*)(Bc + (rB + n * 16) * 32 + chunkOff);
        #pragma unroll
        for (int m = 0; m < 4; ++m)
            #pragma unroll
            for (int n = 0; n < 4; ++n)
                acc[m][n] = MFMA16(aF[m], bF[n], acc[m][n]);

        __syncthreads();
    }

    // epilogue: C/D layout col=lane&15, row=(lane>>4)*4+reg; h store + fused stats
    const int orow = (lane >> 4) * 4;
    float psum[4], psq[4];
    #pragma unroll
    for (int n = 0; n < 4; ++n) { psum[n] = 0.f; psq[n] = 0.f; }
    #pragma unroll
    for (int m = 0; m < 4; ++m) {
        #pragma unroll
        for (int n = 0; n < 4; ++n) {
            int col = colBase + wc * 64 + n * 16 + fr;
            int row = rowBase + wr * 64 + m * 16 + orow;
            #pragma unroll
            for (int j = 0; j < 4; ++j) {
                unsigned short hb = f2bf(acc[m][n][j]);
                float v = bf2f(hb);
                h[(size_t)(row + j) * CC + col] = hb;
                psum[n] += v;
                psq[n]  += v * v;
            }
        }
    }
    #pragma unroll
    for (int n = 0; n < 4; ++n) {
        psum[n] += __shfl_xor(psum[n], 16);
        psum[n] += __shfl_xor(psum[n], 32);
        psq[n]  += __shfl_xor(psq[n], 16);
        psq[n]  += __shfl_xor(psq[n], 32);
    }
    if ((lane >> 4) == 0) {
        #pragma unroll
        for (int n = 0; n < 4; ++n) {
            int cl = wc * 64 + n * 16 + fr;   // local col 0..127
            atomicAdd(&colsum[cl], psum[n]);
            atomicAdd(&colsq[cl],  psq[n]);
        }
    }
    __syncthreads();
    if (tid < 128) {
        int c = colBase + tid;
        atomicAdd(&stats[c],      colsum[tid]);
        atomicAdd(&stats[CC + c], colsq[tid]);
    }
#undef STAGE_A
#undef STAGE_B
}

__global__ void finalize3_k(const float* __restrict__ stats,
                            const float* __restrict__ g1, const float* __restrict__ b1,
                            const float* __restrict__ g2, const float* __restrict__ b2,
                            const float* __restrict__ g3, const float* __restrict__ b3,
                            float* __restrict__ ss) {
    int a = blockIdx.x;
    int c = threadIdx.x;
    const float* g = (a == 0) ? g1 : (a == 1) ? g2 : g3;
    const float* b = (a == 0) ? b1 : (a == 1) ? b2 : b3;
    const float* st = stats + a * 2 * CC;
    float* s = ss + a * 2 * CC;
    float mu  = st[c] * (1.f / NP);
    float var = st[CC + c] * (1.f / NP) - mu * mu;
    float sc  = g[c] * rsqrtf(var + 1e-5f);
    s[c]      = sc;
    s[CC + c] = b[c] - mu * sc;
}

// out = (sigmoid(a1*h1+c1) + sigmoid(a2*h2+c2) + sigmoid(a3*h3+c3)) * feat(bf16)
__global__ void apply3_k(const unsigned short* __restrict__ h1,
                         const unsigned short* __restrict__ h2,
                         const unsigned short* __restrict__ h3,
                         const float* __restrict__ ss,
                         const unsigned short* __restrict__ fb, float* __restrict__ out) {
    size_t e = ((size_t)blockIdx.x * 256 + threadIdx.x) * 8;
    int c0 = (int)(e & (CC - 1));
    bf16x8 v1 = __builtin_nontemporal_load((const bf16x8*)(h1 + e));
    bf16x8 v2 = __builtin_nontemporal_load((const bf16x8*)(h2 + e));
    bf16x8 v3 = __builtin_nontemporal_load((const bf16x8*)(h3 + e));
    bf16x8 fv = *(const bf16x8*)(fb + e);
    float s[8];
    #pragma unroll
    for (int j = 0; j < 8; ++j) {
        float z1 = ss[c0 + j]          * bf2f((unsigned short)v1[j]) + ss[CC + c0 + j];
        float z2 = ss[2 * CC + c0 + j] * bf2f((unsigned short)v2[j]) + ss[3 * CC + c0 + j];
        float z3 = ss[4 * CC + c0 + j] * bf2f((unsigned short)v3[j]) + ss[5 * CC + c0 + j];
        float sg = 1.f / (1.f + __expf(-z1)) + 1.f / (1.f + __expf(-z2)) + 1.f / (1.f + __expf(-z3));
        s[j] = sg * bf2f((unsigned short)fv[j]);
    }
    f32x4* o = (f32x4*)(out + e);
    f32x4 o0 = {s[0], s[1], s[2], s[3]};
    f32x4 o1 = {s[4], s[5], s[6], s[7]};
    __builtin_nontemporal_store(o0, o);
    __builtin_nontemporal_store(o1, o + 1);
}

extern "C" void kernel_launch(void* const* d_in, const int* in_sizes, int n_in,
                              void* d_out, int out_size, void* d_ws, size_t ws_size,
                              hipStream_t stream) {
    const float* feat = (const float*)d_in[0];
    const float* W1   = (const float*)d_in[1];
    const float* W2   = (const float*)d_in[2];
    const float* W3   = (const float*)d_in[3];
    const float* g1   = (const float*)d_in[4];
    const float* b1   = (const float*)d_in[5];
    const float* g2   = (const float*)d_in[6];
    const float* b2   = (const float*)d_in[7];
    const float* g3   = (const float*)d_in[8];
    const float* b3   = (const float*)d_in[9];
    const int* nbr1   = (const int*)d_in[10];
    const int* nbr2   = (const int*)d_in[11];
    const int* nbr3   = (const int*)d_in[12];
    float* out = (float*)d_out;

    char* w = (char*)d_ws;
    unsigned short* fb   = (unsigned short*)w;  w += (size_t)(NP + 1) * CC * 2;
    unsigned short* wbT  = (unsigned short*)w;  w += (size_t)9 * CC * CC * 2;
    float* stats         = (float*)w;           w += (size_t)3 * 2 * CC * 4;
    float* ss            = (float*)w;           w += (size_t)3 * 2 * CC * 4;
    unsigned short* hbuf = (unsigned short*)w;  // 3 * N * C bf16

    cast_all_k<<<NFEAT_BLOCKS + 2304, 256, 0, stream>>>(feat, W1, W2, W3, fb, wbT, stats);

    gemm_conv_fused_k<<<dim3(2048, 3), 256, 0, stream>>>(fb, wbT, nbr1, nbr2, nbr3,
                                                         hbuf, stats);
    finalize3_k<<<3, 256, 0, stream>>>(stats, g1, b1, g2, b2, g3, b3, ss);
    apply3_k<<<16384, 256, 0, stream>>>(hbuf,
                                        hbuf + (size_t)NP * CC,
                                        hbuf + (size_t)2 * NP * CC,
                                        ss, fb, out);
}